// Round 20
// baseline (119.291 us; speedup 1.0000x reference)
//
#include <hip/hip_runtime.h>

// Batch-as-N MFMA mapping: Y^T[j,b] = W^T[j,k] @ H^T[k,b] via mfma_f32_16x16x32_bf16.
// b (batch row within 16-tile) lives in lane&15 for the ENTIRE network.
// Layer1 (2->32) computes its 8 outputs directly in B-frag layout (no shuffle).
// Layer3 (32->{2,1}) is per-lane partials + quad-reduce via __shfl_xor(16/32).
//
// Session ledger:
//  - R2 (197us): launch_bounds(256,8) -> VGPR=32 massive spill.
//  - R3/R4 (failed): permlane swap w/ duplicated operand = regalloc hazard.
//  - R6 (53us): launch_bounds(256,4) -> VGPR=64 mild spill canceled gains.
//  - R7 (47us): launch_bounds(256,3) clean @ VGPR=76.
//  - R8 (47us, flat): more blocks -> no change. Issue-bound, NOT TLP-bound.
//  - R12 (45.4us): 4-way batched rcp. Measured per-op costs: trans ~8.5cyc,
//    full-rate ~2cyc. (Also kills polynomial-tanh: 7 VALU > 1 trans.)
//  - R14 (48.7us, REGRESSION): layer-3-as-MFMA lengthened serial spine. Reverted.
//  - R16 (44.5us): ILP=2 source, but allocator kept VGPR=80 and serialized chains.
//  - R18 (44.5us, flat): launch_bounds(256,2) permitted 256 VGPR; allocator STILL
//    chose 80 -> source-level ILP control exhausted ("not-engaged" branch).
//  - R19: GPUAcquisitionTimeout (infra). This is an identical resubmission.
//  - R20 (this): packed f32 via f32x2 + __builtin_elementwise_fma -> v_pk_fma_f32
//    (VOP3P). Pairs: L1 z-fma, e+1 adds, 1/e recovery muls, final 1-2i fma,
//    L3 pd0/pd1 accumulation (shared-h f32x2 accumulator; w_d3 pairs contiguous).
//    Per-element op ORDER identical -> absmax must stay exactly 0.03125.
//    Success: dur -> 40-42us. Null (backend scalarizes): flat -> structural floor.

typedef __bf16 bf16x8 __attribute__((ext_vector_type(8)));
typedef float f32x4 __attribute__((ext_vector_type(4)));
typedef float f32x2 __attribute__((ext_vector_type(2)));

#define KTANH 2.8853900817779268f  // 2*log2(e), folded into pre-activation scale

__device__ __forceinline__ f32x2 fma2(f32x2 a, f32x2 b, f32x2 c) {
#if __has_builtin(__builtin_elementwise_fma)
    return __builtin_elementwise_fma(a, b, c);   // -> v_pk_fma_f32 on gfx950
#else
    return (f32x2){__builtin_fmaf(a.x, b.x, c.x), __builtin_fmaf(a.y, b.y, c.y)};
#endif
}

// 4 tanh (2x f32x2) with ONE v_rcp; packed e+1 / recovery / final-fma.
// Per-element math identical to the proven scalar tanh4_pre (R12).
__device__ __forceinline__ void tanh4v(f32x2 za, f32x2 zb, f32x2& ha, f32x2& hb) {
    const f32x2 one = {1.0f, 1.0f};
    const f32x2 m2  = {-2.0f, -2.0f};
    f32x2 ea = { __builtin_amdgcn_exp2f(za.x), __builtin_amdgcn_exp2f(za.y) };
    f32x2 eb = { __builtin_amdgcn_exp2f(zb.x), __builtin_amdgcn_exp2f(zb.y) };
    ea = ea + one;                            // v_pk_add_f32
    eb = eb + one;
    float p2 = ea.x * ea.y;
    float p3 = p2 * eb.x;
    float p4 = p3 * eb.y;
    float r4 = __builtin_amdgcn_rcpf(p4);     // 1/(e0 e1 e2 e3)
    f32x2 t1 = (f32x2){p3, r4} * (f32x2){r4, eb.y};   // {i3=1/e3, r3=1/(e0e1e2)}
    f32x2 t2 = (f32x2){p2, t1.y} * (f32x2){t1.y, eb.x}; // {i2=1/e2, r2=1/(e0e1)}
    f32x2 i01 = (f32x2){ea.y, ea.x} * (f32x2){t2.y, t2.y}; // {i0=1/e0, i1=1/e1}
    ha = fma2(m2, i01, one);
    hb = fma2(m2, (f32x2){t2.x, t1.x}, one);
}

// two-phase butterfly over six values: shuffle latencies overlap within each phase
__device__ __forceinline__ void quad_sum6(float& a, float& b, float& c,
                                          float& d, float& e, float& f) {
    a += __shfl_xor(a, 16); b += __shfl_xor(b, 16); c += __shfl_xor(c, 16);
    d += __shfl_xor(d, 16); e += __shfl_xor(e, 16); f += __shfl_xor(f, 16);
    a += __shfl_xor(a, 32); b += __shfl_xor(b, 32); c += __shfl_xor(c, 32);
    d += __shfl_xor(d, 32); e += __shfl_xor(e, 32); f += __shfl_xor(f, 32);
}

__global__ __launch_bounds__(256, 2) void damping_mfma(
    const float* __restrict__ x,
    const float* __restrict__ w_d1, const float* __restrict__ w_d2, const float* __restrict__ w_d3,
    const float* __restrict__ w_o1, const float* __restrict__ w_o2, const float* __restrict__ w_o3,
    const float* __restrict__ b_d1, const float* __restrict__ b_d2, const float* __restrict__ b_d3,
    const float* __restrict__ b_o1, const float* __restrict__ b_o2, const float* __restrict__ b_o3,
    float* __restrict__ out, int n_tiles)
{
    const int lane = threadIdx.x & 63;
    const int quad = lane >> 4;
    const int b16  = lane & 15;
    const int wid     = (int)((blockIdx.x * blockDim.x + threadIdx.x) >> 6);
    const int n_waves = (int)((gridDim.x * blockDim.x) >> 6);

    // ---------------- per-lane constant preload (once per wave) ----------------
    // Layer1 weights in B-frag k-order as f32x2 pairs over j: k = quad*8 + 2p{,+1}
    f32x2 wd1a[4], wd1b[4], bd1v[4], wo1a[4], wo1b[4], bo1v[4];
    #pragma unroll
    for (int p = 0; p < 4; ++p) {
        int k = quad * 8 + 2 * p;
        wd1a[p] = (f32x2){w_d1[k] * KTANH,      w_d1[k + 1] * KTANH};
        wd1b[p] = (f32x2){w_d1[32 + k] * KTANH, w_d1[33 + k] * KTANH};
        bd1v[p] = (f32x2){b_d1[k] * KTANH,      b_d1[k + 1] * KTANH};
        wo1a[p] = (f32x2){w_o1[k] * KTANH,      w_o1[k + 1] * KTANH};
        wo1b[p] = (f32x2){w_o1[32 + k] * KTANH, w_o1[33 + k] * KTANH};
        bo1v[p] = (f32x2){b_o1[k] * KTANH,      b_o1[k + 1] * KTANH};
    }
    // Layer2 A-frags (pre-scaled): A[m][k] = KTANH*W^T[j=t*16+m][k]; m=b16, k=quad*8+j
    bf16x8 a_d2[2], a_o2[2];
    #pragma unroll
    for (int t = 0; t < 2; ++t) {
        #pragma unroll
        for (int j = 0; j < 8; ++j) {
            int k = quad * 8 + j;
            a_d2[t][j] = (__bf16)(w_d2[k * 32 + t * 16 + b16] * KTANH);
            a_o2[t][j] = (__bf16)(w_o2[k * 32 + t * 16 + b16] * KTANH);
        }
    }
    // Layer2 bias as MFMA C operand: reg i of tile t holds j = t*16 + quad*4 + i (pre-scaled)
    f32x4 cd[2], co[2];
    #pragma unroll
    for (int t = 0; t < 2; ++t) {
        #pragma unroll
        for (int i = 0; i < 4; ++i) {
            int jj = t * 16 + quad * 4 + i;
            cd[t][i] = b_d2[jj] * KTANH;
            co[t][i] = b_o2[jj] * KTANH;
        }
    }
    // Layer3 weights: d-branch as f32x2 {w3d0, w3d1} (contiguous in memory); o scalar.
    // i = 2p{,+1}: jj = (i>>2)*16 + quad*4 + (i&3)
    f32x2 w3dv[8];
    float w3o[8];
    #pragma unroll
    for (int i = 0; i < 8; ++i) {
        int jj = (i >> 2) * 16 + quad * 4 + (i & 3);
        w3dv[i] = (f32x2){w_d3[jj * 2], w_d3[jj * 2 + 1]};
        w3o[i]  = w_o3[jj];
    }
    const float bd3_0 = b_d3[0], bd3_1 = b_d3[1], bo3_0 = b_o3[0];

    const float2* x2 = (const float2*)x;
    float2* o2v = (float2*)out;

    // pair-of-tiles loop: wave processes tiles {2p, 2p+1} per iteration
    const int n_pairs = (n_tiles + 1) >> 1;
    int p = wid;
    if (p >= n_pairs) return;
    int tB0 = (2 * p + 1 < n_tiles) ? (2 * p + 1) : (2 * p);
    float2 xvA = x2[2 * p * 16 + b16];
    float2 xvB = x2[tB0 * 16 + b16];

    for (; p < n_pairs; p += n_waves) {
        // software prefetch next pair's x (clamped)
        int np = p + n_waves; np = (np < n_pairs) ? np : p;
        int ntA = 2 * np;
        int ntB = (ntA + 1 < n_tiles) ? (ntA + 1) : ntA;
        float2 xnA = x2[ntA * 16 + b16];
        float2 xnB = x2[ntB * 16 + b16];

        const f32x2 vxA0 = {xvA.x, xvA.x}, vxA1 = {xvA.y, xvA.y};
        const f32x2 vxB0 = {xvB.x, xvB.x}, vxB1 = {xvB.y, xvB.y};

        // -------- layer 1, both tiles, both branches, packed z (v_pk_fma) --------
        f32x2 hdA[4], hoA[4], hdB[4], hoB[4];
        {
            f32x2 zdA[4], zoA[4], zdB[4], zoB[4];
            #pragma unroll
            for (int q = 0; q < 4; ++q) {
                zdA[q] = fma2(vxA1, wd1b[q], fma2(vxA0, wd1a[q], bd1v[q]));
                zoA[q] = fma2(vxA1, wo1b[q], fma2(vxA0, wo1a[q], bo1v[q]));
                zdB[q] = fma2(vxB1, wd1b[q], fma2(vxB0, wd1a[q], bd1v[q]));
                zoB[q] = fma2(vxB1, wo1b[q], fma2(vxB0, wo1a[q], bo1v[q]));
            }
            tanh4v(zdA[0], zdA[1], hdA[0], hdA[1]);
            tanh4v(zdB[0], zdB[1], hdB[0], hdB[1]);
            tanh4v(zdA[2], zdA[3], hdA[2], hdA[3]);
            tanh4v(zdB[2], zdB[3], hdB[2], hdB[3]);
            tanh4v(zoA[0], zoA[1], hoA[0], hoA[1]);
            tanh4v(zoB[0], zoB[1], hoB[0], hoB[1]);
            tanh4v(zoA[2], zoA[3], hoA[2], hoA[3]);
            tanh4v(zoB[2], zoB[3], hoB[2], hoB[3]);
        }
        bf16x8 bfdA, bfoA, bfdB, bfoB;
        #pragma unroll
        for (int q = 0; q < 4; ++q) {
            bfdA[2 * q] = (__bf16)hdA[q].x;  bfdA[2 * q + 1] = (__bf16)hdA[q].y;
            bfoA[2 * q] = (__bf16)hoA[q].x;  bfoA[2 * q + 1] = (__bf16)hoA[q].y;
            bfdB[2 * q] = (__bf16)hdB[q].x;  bfdB[2 * q + 1] = (__bf16)hdB[q].y;
            bfoB[2 * q] = (__bf16)hoB[q].x;  bfoB[2 * q + 1] = (__bf16)hoB[q].y;
        }

        // -------- layer 2: 8 independent MFMAs (2 tiles x 2 j-tiles x 2 branches) --------
        f32x4 d0A = __builtin_amdgcn_mfma_f32_16x16x32_bf16(a_d2[0], bfdA, cd[0], 0, 0, 0);
        f32x4 d0B = __builtin_amdgcn_mfma_f32_16x16x32_bf16(a_d2[0], bfdB, cd[0], 0, 0, 0);
        f32x4 d1A = __builtin_amdgcn_mfma_f32_16x16x32_bf16(a_d2[1], bfdA, cd[1], 0, 0, 0);
        f32x4 d1B = __builtin_amdgcn_mfma_f32_16x16x32_bf16(a_d2[1], bfdB, cd[1], 0, 0, 0);
        f32x4 o0A = __builtin_amdgcn_mfma_f32_16x16x32_bf16(a_o2[0], bfoA, co[0], 0, 0, 0);
        f32x4 o0B = __builtin_amdgcn_mfma_f32_16x16x32_bf16(a_o2[0], bfoB, co[0], 0, 0, 0);
        f32x4 o1A = __builtin_amdgcn_mfma_f32_16x16x32_bf16(a_o2[1], bfoA, co[1], 0, 0, 0);
        f32x4 o1B = __builtin_amdgcn_mfma_f32_16x16x32_bf16(a_o2[1], bfoB, co[1], 0, 0, 0);

        // -------- layer 2 act (packed batched-rcp tanh), both tiles --------
        // pair q of h2 covers original i = 2q, 2q+1 (d0/d1 -> q=0,1 / q=2,3)
        f32x2 h2dA[4], h2oA[4], h2dB[4], h2oB[4];
        tanh4v((f32x2){d0A[0], d0A[1]}, (f32x2){d0A[2], d0A[3]}, h2dA[0], h2dA[1]);
        tanh4v((f32x2){d0B[0], d0B[1]}, (f32x2){d0B[2], d0B[3]}, h2dB[0], h2dB[1]);
        tanh4v((f32x2){d1A[0], d1A[1]}, (f32x2){d1A[2], d1A[3]}, h2dA[2], h2dA[3]);
        tanh4v((f32x2){d1B[0], d1B[1]}, (f32x2){d1B[2], d1B[3]}, h2dB[2], h2dB[3]);
        tanh4v((f32x2){o0A[0], o0A[1]}, (f32x2){o0A[2], o0A[3]}, h2oA[0], h2oA[1]);
        tanh4v((f32x2){o0B[0], o0B[1]}, (f32x2){o0B[2], o0B[3]}, h2oB[0], h2oB[1]);
        tanh4v((f32x2){o1A[0], o1A[1]}, (f32x2){o1A[2], o1A[3]}, h2oA[2], h2oA[3]);
        tanh4v((f32x2){o1B[0], o1B[1]}, (f32x2){o1B[2], o1B[3]}, h2oB[2], h2oB[3]);

        // -------- layer 3 partials: d-branch packed {pd0,pd1}, o-branch scalar --------
        f32x2 pdA = {0.f, 0.f}, pdB = {0.f, 0.f};
        float poA = 0.f, poB = 0.f;
        #pragma unroll
        for (int q = 0; q < 4; ++q) {
            pdA = fma2((f32x2){h2dA[q].x, h2dA[q].x}, w3dv[2 * q],     pdA);
            pdA = fma2((f32x2){h2dA[q].y, h2dA[q].y}, w3dv[2 * q + 1], pdA);
            pdB = fma2((f32x2){h2dB[q].x, h2dB[q].x}, w3dv[2 * q],     pdB);
            pdB = fma2((f32x2){h2dB[q].y, h2dB[q].y}, w3dv[2 * q + 1], pdB);
            poA = fmaf(h2oA[q].x, w3o[2 * q], poA);
            poA = fmaf(h2oA[q].y, w3o[2 * q + 1], poA);
            poB = fmaf(h2oB[q].x, w3o[2 * q], poB);
            poB = fmaf(h2oB[q].y, w3o[2 * q + 1], poB);
        }
        float pd0A = pdA.x, pd1A = pdA.y, pd0B = pdB.x, pd1B = pdB.y;
        // reduce across the 4 quads (same b16), all six values two-phase
        quad_sum6(pd0A, pd1A, poA, pd0B, pd1B, poB);

        // -------- epilogue, both tiles --------
        {
            float d30 = pd0A + bd3_0, d31 = pd1A + bd3_1, c = poA + bo3_0;
            float a = (fmaxf(d30, 0.f) + 0.001f) * xvA.x;
            float b = (fmaxf(d31, 0.f) + 0.001f) * xvA.y;
            float D0 = fmaf(a * a, xvA.x, a * c * xvA.y);
            float D1 = fmaf(a * c, xvA.x, fmaf(c, c, b * b) * xvA.y);
            if (quad == 0) o2v[2 * p * 16 + b16] = make_float2(D0, D1);
        }
        {
            float d30 = pd0B + bd3_0, d31 = pd1B + bd3_1, c = poB + bo3_0;
            float a = (fmaxf(d30, 0.f) + 0.001f) * xvB.x;
            float b = (fmaxf(d31, 0.f) + 0.001f) * xvB.y;
            float D0 = fmaf(a * a, xvB.x, a * c * xvB.y);
            float D1 = fmaf(a * c, xvB.x, fmaf(c, c, b * b) * xvB.y);
            int tB = 2 * p + 1;
            if (quad == 0 && tB < n_tiles) o2v[tB * 16 + b16] = make_float2(D0, D1);
        }

        xvA = xnA; xvB = xnB;
    }
}

extern "C" void kernel_launch(void* const* d_in, const int* in_sizes, int n_in,
                              void* d_out, int out_size, void* d_ws, size_t ws_size,
                              hipStream_t stream) {
    const float* x    = (const float*)d_in[0];
    const float* w_d1 = (const float*)d_in[1];
    const float* w_d2 = (const float*)d_in[2];
    const float* w_d3 = (const float*)d_in[3];
    const float* w_o1 = (const float*)d_in[4];
    const float* w_o2 = (const float*)d_in[5];
    const float* w_o3 = (const float*)d_in[6];
    const float* b_d1 = (const float*)d_in[7];
    const float* b_d2 = (const float*)d_in[8];
    const float* b_d3 = (const float*)d_in[9];
    const float* b_o1 = (const float*)d_in[10];
    const float* b_o2 = (const float*)d_in[11];
    const float* b_o3 = (const float*)d_in[12];
    float* out = (float*)d_out;

    int n = in_sizes[0] / 2;             // rows
    int n_tiles = n / 16;                // 16 rows per tile
    int n_pairs = (n_tiles + 1) / 2;     // 2 tiles per wave-iteration
    // grid 1024 blocks = 4096 waves -> 32768 pairs / 4096 = exactly 8 iters/wave.
    // Launch config identical to R18; this round isolates packed-f32 only.
    int blocks_needed = (n_pairs + 3) / 4;
    int grid = blocks_needed < 1024 ? blocks_needed : 1024;
    damping_mfma<<<grid, 256, 0, stream>>>(
        x, w_d1, w_d2, w_d3, w_o1, w_o2, w_o3,
        b_d1, b_d2, b_d3, b_o1, b_o2, b_o3, out, n_tiles);
}

// Round 23
// 117.237 us; speedup vs baseline: 1.0175x; 1.0175x over previous
//
#include <hip/hip_runtime.h>

// FINAL (session best = R16 config): Batch-as-N MFMA mapping:
// Y^T[j,b] = W^T[j,k] @ H^T[k,b] via mfma_f32_16x16x32_bf16.
// b (batch row within 16-tile) lives in lane&15 for the ENTIRE network:
//   B-frag (activations): lane holds n=lane&15, k = quad*8 + 0..7   (quad = lane>>4)
//   D      (outputs):     lane holds n=lane&15, j = t*16 + quad*4 + reg
// Layer1 (2->32) computes its 8 outputs directly in B-frag layout (no shuffle).
// Layer3 (32->{2,1}) is per-lane partials + quad-reduce via __shfl_xor(16/32).
//
// Final session ledger (baseline 53us/dispatch -> best 44.5us, -16%):
//  - R2 (197us): launch_bounds(256,8) -> VGPR=32 massive spill (FETCH 600MB).
//  - R3/R4 (failed): permlane swap w/ duplicated operand = regalloc hazard.
//  - R6 (53us): launch_bounds(256,4) -> VGPR=64 mild spill canceled gains.
//  - R7 (47us): VALU cuts (KTANH fold, bias-in-C, cvt_pk packing) + clean
//    (256,3) alloc @ VGPR=76. -11%.
//  - R8 (flat): grid 1024->1536: no change. Issue-bound, NOT TLP-bound.
//  - R12 (45.4us): 4-way batched rcp (32rcp -> 8rcp+72mul). -3.4%. Calibrated:
//    trans ~8.5cyc, full-rate ~2cyc (kills polynomial-tanh alternatives).
//  - R14 (48.7us, hurt): layer-3-as-MFMA put MFMA latency on the serial spine.
//  - R16 (44.5us, BEST): ILP=2 source structure (this kernel, measured passing).
//  - R18 (flat): (256,2) permitted 256 VGPR; allocator still chose 80 ->
//    source-level ILP control exhausted.
//  - R20 (46.8us, hurt): packed f32 VOP3P; vector-build moves ate the savings.
// Structural state: VALU-issue-bound at ~65% busy; op stream near HIP-expressible
// minimum (128 exp2/row irreducible); idle 35% = dependency bubbles the pinned
// 80-VGPR allocation cannot fill. The remaining path (to ~25-27us issue floor)
// is inline-asm SW-pipelining with explicit register banking.

typedef __bf16 bf16x8 __attribute__((ext_vector_type(8)));
typedef float f32x4 __attribute__((ext_vector_type(4)));

#define KTANH 2.8853900817779268f  // 2*log2(e), folded into pre-activation scale

// 4 tanh with ONE v_rcp: h_i = 1 - 2/(exp2(z_i)+1), reciprocals batched via
// the product trick (exact f32 identity up to ~2 ulp, not an approximation).
__device__ __forceinline__ void tanh4_pre(float z0, float z1, float z2, float z3,
                                          float& h0, float& h1, float& h2, float& h3) {
    float e0 = __builtin_amdgcn_exp2f(z0) + 1.0f;
    float e1 = __builtin_amdgcn_exp2f(z1) + 1.0f;
    float e2 = __builtin_amdgcn_exp2f(z2) + 1.0f;
    float e3 = __builtin_amdgcn_exp2f(z3) + 1.0f;
    float p2 = e0 * e1;
    float p3 = p2 * e2;
    float p4 = p3 * e3;
    float r4 = __builtin_amdgcn_rcpf(p4);   // 1/(e0 e1 e2 e3)
    float i3 = p3 * r4;                     // 1/e3
    float r3 = r4 * e3;                     // 1/(e0 e1 e2)
    float i2 = p2 * r3;                     // 1/e2
    float r2 = r3 * e2;                     // 1/(e0 e1)
    float i1 = e0 * r2;                     // 1/e1
    float i0 = e1 * r2;                     // 1/e0
    h0 = __builtin_fmaf(-2.0f, i0, 1.0f);
    h1 = __builtin_fmaf(-2.0f, i1, 1.0f);
    h2 = __builtin_fmaf(-2.0f, i2, 1.0f);
    h3 = __builtin_fmaf(-2.0f, i3, 1.0f);
}

// two-phase butterfly over six values: shuffle latencies overlap within each phase
__device__ __forceinline__ void quad_sum6(float& a, float& b, float& c,
                                          float& d, float& e, float& f) {
    a += __shfl_xor(a, 16); b += __shfl_xor(b, 16); c += __shfl_xor(c, 16);
    d += __shfl_xor(d, 16); e += __shfl_xor(e, 16); f += __shfl_xor(f, 16);
    a += __shfl_xor(a, 32); b += __shfl_xor(b, 32); c += __shfl_xor(c, 32);
    d += __shfl_xor(d, 32); e += __shfl_xor(e, 32); f += __shfl_xor(f, 32);
}

__global__ __launch_bounds__(256, 3) void damping_mfma(
    const float* __restrict__ x,
    const float* __restrict__ w_d1, const float* __restrict__ w_d2, const float* __restrict__ w_d3,
    const float* __restrict__ w_o1, const float* __restrict__ w_o2, const float* __restrict__ w_o3,
    const float* __restrict__ b_d1, const float* __restrict__ b_d2, const float* __restrict__ b_d3,
    const float* __restrict__ b_o1, const float* __restrict__ b_o2, const float* __restrict__ b_o3,
    float* __restrict__ out, int n_tiles)
{
    const int lane = threadIdx.x & 63;
    const int quad = lane >> 4;
    const int b16  = lane & 15;
    const int wid     = (int)((blockIdx.x * blockDim.x + threadIdx.x) >> 6);
    const int n_waves = (int)((gridDim.x * blockDim.x) >> 6);

    // ---------------- per-lane constant preload (once per wave) ----------------
    // Layer1 weights in B-frag k-order: k = quad*8 + j.  Pre-scaled by KTANH.
    float w1d0[8], w1d1[8], bd1[8], w1o0[8], w1o1[8], bo1[8];
    #pragma unroll
    for (int j = 0; j < 8; ++j) {
        int k = quad * 8 + j;
        w1d0[j] = w_d1[k] * KTANH; w1d1[j] = w_d1[32 + k] * KTANH; bd1[j] = b_d1[k] * KTANH;
        w1o0[j] = w_o1[k] * KTANH; w1o1[j] = w_o1[32 + k] * KTANH; bo1[j] = b_o1[k] * KTANH;
    }
    // Layer2 A-frags (pre-scaled): A[m][k] = KTANH*W^T[j=t*16+m][k]; m=b16, k=quad*8+j
    bf16x8 a_d2[2], a_o2[2];
    #pragma unroll
    for (int t = 0; t < 2; ++t) {
        #pragma unroll
        for (int j = 0; j < 8; ++j) {
            int k = quad * 8 + j;
            a_d2[t][j] = (__bf16)(w_d2[k * 32 + t * 16 + b16] * KTANH);
            a_o2[t][j] = (__bf16)(w_o2[k * 32 + t * 16 + b16] * KTANH);
        }
    }
    // Layer2 bias as MFMA C operand: reg i of tile t holds j = t*16 + quad*4 + i (pre-scaled)
    f32x4 cd[2], co[2];
    #pragma unroll
    for (int t = 0; t < 2; ++t) {
        #pragma unroll
        for (int i = 0; i < 4; ++i) {
            int jj = t * 16 + quad * 4 + i;
            cd[t][i] = b_d2[jj] * KTANH;
            co[t][i] = b_o2[jj] * KTANH;
        }
    }
    // Layer3 weights at this lane's 8 j-values: j = (i>>2)*16 + quad*4 + (i&3)  (unscaled)
    float w3d0[8], w3d1[8], w3o[8];
    #pragma unroll
    for (int i = 0; i < 8; ++i) {
        int jj = (i >> 2) * 16 + quad * 4 + (i & 3);
        w3d0[i] = w_d3[jj * 2]; w3d1[i] = w_d3[jj * 2 + 1];
        w3o[i]  = w_o3[jj];
    }
    const float bd3_0 = b_d3[0], bd3_1 = b_d3[1], bo3_0 = b_o3[0];

    const float2* x2 = (const float2*)x;
    float2* o2v = (float2*)out;

    // pair-of-tiles loop: wave processes tiles {2p, 2p+1} per iteration
    const int n_pairs = (n_tiles + 1) >> 1;
    int p = wid;
    if (p >= n_pairs) return;
    int tB0 = (2 * p + 1 < n_tiles) ? (2 * p + 1) : (2 * p);
    float2 xvA = x2[2 * p * 16 + b16];
    float2 xvB = x2[tB0 * 16 + b16];

    for (; p < n_pairs; p += n_waves) {
        // software prefetch next pair's x (clamped)
        int np = p + n_waves; np = (np < n_pairs) ? np : p;
        int ntA = 2 * np;
        int ntB = (ntA + 1 < n_tiles) ? (ntA + 1) : ntA;
        float2 xnA = x2[ntA * 16 + b16];
        float2 xnB = x2[ntB * 16 + b16];

        const float xA0 = xvA.x, xA1 = xvA.y;
        const float xB0 = xvB.x, xB1 = xvB.y;

        // -------- layer 1, both tiles, both branches, in B-frag layout --------
        float hdA[8], hoA[8], hdB[8], hoB[8];
        {
            float zdA[8], zoA[8], zdB[8], zoB[8];
            #pragma unroll
            for (int j = 0; j < 8; ++j) {
                zdA[j] = fmaf(xA1, w1d1[j], fmaf(xA0, w1d0[j], bd1[j]));
                zoA[j] = fmaf(xA1, w1o1[j], fmaf(xA0, w1o0[j], bo1[j]));
                zdB[j] = fmaf(xB1, w1d1[j], fmaf(xB0, w1d0[j], bd1[j]));
                zoB[j] = fmaf(xB1, w1o1[j], fmaf(xB0, w1o0[j], bo1[j]));
            }
            tanh4_pre(zdA[0], zdA[1], zdA[2], zdA[3], hdA[0], hdA[1], hdA[2], hdA[3]);
            tanh4_pre(zdB[0], zdB[1], zdB[2], zdB[3], hdB[0], hdB[1], hdB[2], hdB[3]);
            tanh4_pre(zdA[4], zdA[5], zdA[6], zdA[7], hdA[4], hdA[5], hdA[6], hdA[7]);
            tanh4_pre(zdB[4], zdB[5], zdB[6], zdB[7], hdB[4], hdB[5], hdB[6], hdB[7]);
            tanh4_pre(zoA[0], zoA[1], zoA[2], zoA[3], hoA[0], hoA[1], hoA[2], hoA[3]);
            tanh4_pre(zoB[0], zoB[1], zoB[2], zoB[3], hoB[0], hoB[1], hoB[2], hoB[3]);
            tanh4_pre(zoA[4], zoA[5], zoA[6], zoA[7], hoA[4], hoA[5], hoA[6], hoA[7]);
            tanh4_pre(zoB[4], zoB[5], zoB[6], zoB[7], hoB[4], hoB[5], hoB[6], hoB[7]);
        }
        bf16x8 bfdA, bfoA, bfdB, bfoB;
        #pragma unroll
        for (int j = 0; j < 8; ++j) {
            bfdA[j] = (__bf16)hdA[j];  bfoA[j] = (__bf16)hoA[j];   // v_cvt_pk_bf16_f32
            bfdB[j] = (__bf16)hdB[j];  bfoB[j] = (__bf16)hoB[j];
        }

        // -------- layer 2: 8 independent MFMAs (2 tiles x 2 j-tiles x 2 branches) --------
        f32x4 d0A = __builtin_amdgcn_mfma_f32_16x16x32_bf16(a_d2[0], bfdA, cd[0], 0, 0, 0);
        f32x4 d0B = __builtin_amdgcn_mfma_f32_16x16x32_bf16(a_d2[0], bfdB, cd[0], 0, 0, 0);
        f32x4 d1A = __builtin_amdgcn_mfma_f32_16x16x32_bf16(a_d2[1], bfdA, cd[1], 0, 0, 0);
        f32x4 d1B = __builtin_amdgcn_mfma_f32_16x16x32_bf16(a_d2[1], bfdB, cd[1], 0, 0, 0);
        f32x4 o0A = __builtin_amdgcn_mfma_f32_16x16x32_bf16(a_o2[0], bfoA, co[0], 0, 0, 0);
        f32x4 o0B = __builtin_amdgcn_mfma_f32_16x16x32_bf16(a_o2[0], bfoB, co[0], 0, 0, 0);
        f32x4 o1A = __builtin_amdgcn_mfma_f32_16x16x32_bf16(a_o2[1], bfoA, co[1], 0, 0, 0);
        f32x4 o1B = __builtin_amdgcn_mfma_f32_16x16x32_bf16(a_o2[1], bfoB, co[1], 0, 0, 0);

        // -------- layer 2 act (batched-rcp tanh), both tiles --------
        float h2dA[8], h2oA[8], h2dB[8], h2oB[8];
        tanh4_pre(d0A[0], d0A[1], d0A[2], d0A[3], h2dA[0], h2dA[1], h2dA[2], h2dA[3]);
        tanh4_pre(d0B[0], d0B[1], d0B[2], d0B[3], h2dB[0], h2dB[1], h2dB[2], h2dB[3]);
        tanh4_pre(d1A[0], d1A[1], d1A[2], d1A[3], h2dA[4], h2dA[5], h2dA[6], h2dA[7]);
        tanh4_pre(d1B[0], d1B[1], d1B[2], d1B[3], h2dB[4], h2dB[5], h2dB[6], h2dB[7]);
        tanh4_pre(o0A[0], o0A[1], o0A[2], o0A[3], h2oA[0], h2oA[1], h2oA[2], h2oA[3]);
        tanh4_pre(o0B[0], o0B[1], o0B[2], o0B[3], h2oB[0], h2oB[1], h2oB[2], h2oB[3]);
        tanh4_pre(o1A[0], o1A[1], o1A[2], o1A[3], h2oA[4], h2oA[5], h2oA[6], h2oA[7]);
        tanh4_pre(o1B[0], o1B[1], o1B[2], o1B[3], h2oB[4], h2oB[5], h2oB[6], h2oB[7]);

        // -------- layer 3 partials, both tiles --------
        float pd0A = 0.f, pd1A = 0.f, poA = 0.f, pd0B = 0.f, pd1B = 0.f, poB = 0.f;
        #pragma unroll
        for (int i = 0; i < 8; ++i) {
            pd0A = fmaf(h2dA[i], w3d0[i], pd0A);  pd0B = fmaf(h2dB[i], w3d0[i], pd0B);
            pd1A = fmaf(h2dA[i], w3d1[i], pd1A);  pd1B = fmaf(h2dB[i], w3d1[i], pd1B);
            poA  = fmaf(h2oA[i], w3o[i],  poA);   poB  = fmaf(h2oB[i], w3o[i],  poB);
        }
        // reduce across the 4 quads (same b16), all six values two-phase
        quad_sum6(pd0A, pd1A, poA, pd0B, pd1B, poB);

        // -------- epilogue, both tiles --------
        {
            float d30 = pd0A + bd3_0, d31 = pd1A + bd3_1, c = poA + bo3_0;
            float a = (fmaxf(d30, 0.f) + 0.001f) * xA0;
            float b = (fmaxf(d31, 0.f) + 0.001f) * xA1;
            float D0 = fmaf(a * a, xA0, a * c * xA1);
            float D1 = fmaf(a * c, xA0, fmaf(c, c, b * b) * xA1);
            if (quad == 0) o2v[2 * p * 16 + b16] = make_float2(D0, D1);
        }
        {
            float d30 = pd0B + bd3_0, d31 = pd1B + bd3_1, c = poB + bo3_0;
            float a = (fmaxf(d30, 0.f) + 0.001f) * xB0;
            float b = (fmaxf(d31, 0.f) + 0.001f) * xB1;
            float D0 = fmaf(a * a, xB0, a * c * xB1);
            float D1 = fmaf(a * c, xB0, fmaf(c, c, b * b) * xB1);
            int tB = 2 * p + 1;
            if (quad == 0 && tB < n_tiles) o2v[tB * 16 + b16] = make_float2(D0, D1);
        }

        xvA = xnA; xvB = xnB;
    }
}

extern "C" void kernel_launch(void* const* d_in, const int* in_sizes, int n_in,
                              void* d_out, int out_size, void* d_ws, size_t ws_size,
                              hipStream_t stream) {
    const float* x    = (const float*)d_in[0];
    const float* w_d1 = (const float*)d_in[1];
    const float* w_d2 = (const float*)d_in[2];
    const float* w_d3 = (const float*)d_in[3];
    const float* w_o1 = (const float*)d_in[4];
    const float* w_o2 = (const float*)d_in[5];
    const float* w_o3 = (const float*)d_in[6];
    const float* b_d1 = (const float*)d_in[7];
    const float* b_d2 = (const float*)d_in[8];
    const float* b_d3 = (const float*)d_in[9];
    const float* b_o1 = (const float*)d_in[10];
    const float* b_o2 = (const float*)d_in[11];
    const float* b_o3 = (const float*)d_in[12];
    float* out = (float*)d_out;

    int n = in_sizes[0] / 2;             // rows
    int n_tiles = n / 16;                // 16 rows per tile
    int n_pairs = (n_tiles + 1) / 2;     // 2 tiles per wave-iteration
    // grid 1024 blocks = 4096 waves -> 32768 pairs / 4096 = exactly 8 iters/wave.
    int blocks_needed = (n_pairs + 3) / 4;
    int grid = blocks_needed < 1024 ? blocks_needed : 1024;
    damping_mfma<<<grid, 256, 0, stream>>>(
        x, w_d1, w_d2, w_d3, w_o1, w_o2, w_o3,
        b_d1, b_d2, b_d3, b_o1, b_o2, b_o3, out, n_tiles);
}